// Round 3
// baseline (110.042 us; speedup 1.0000x reference)
//
#include <hip/hip_runtime.h>
#include <hip/hip_bf16.h>

#define BB 4
#define TT 2048
#define CC 1024
#define HH 64
#define LOG2E 1.4426950408889634f

typedef __attribute__((ext_vector_type(8))) unsigned short ushort8;
typedef __attribute__((ext_vector_type(4))) unsigned short ushort4v;
typedef __attribute__((ext_vector_type(8))) __bf16 bf16x8;
typedef __attribute__((ext_vector_type(4))) float float4v;

static __device__ __forceinline__ unsigned short f2bf(float f) {
    return __builtin_bit_cast(unsigned short, (__bf16)f);  // RNE, hw cvt
}

static __device__ __forceinline__ float4v mfma16(ushort8 a, ushort8 b, float4v c) {
    return __builtin_amdgcn_mfma_f32_16x16x32_bf16(
        __builtin_bit_cast(bf16x8, a), __builtin_bit_cast(bf16x8, b), c, 0, 0, 0);
}

static __device__ __forceinline__ ushort8 cvt8(float4v a, float4v b) {
    ushort8 r;
#pragma unroll
    for (int i = 0; i < 4; ++i) { r[i] = f2bf(a[i]); r[4 + i] = f2bf(b[i]); }
    return r;
}

// ---------------------------------------------------------------------------
// Kernel 0: W (f32 [C][H]) -> W^T bf16 [3][H][C] (k-contiguous), once.
// ---------------------------------------------------------------------------
__global__ __launch_bounds__(256) void wconv_kernel(
    const float* __restrict__ Wq, const float* __restrict__ Wk,
    const float* __restrict__ Wv, unsigned short* __restrict__ wt)
{
    const int bidx = blockIdx.x;
    const int y = bidx >> 6, n = bidx & 63;
    const float* __restrict__ W = (y == 0) ? Wq : (y == 1) ? Wk : Wv;
    const int k0 = threadIdx.x << 2;
    ushort4v p;
#pragma unroll
    for (int i = 0; i < 4; ++i) p[i] = f2bf(W[(size_t)(k0 + i) * HH + n]);
    *(ushort4v*)&wt[((size_t)y * HH + n) * CC + k0] = p;
}

// ---------------------------------------------------------------------------
// Kernel 1: fused q/k/v projection. NO LDS, NO barriers.
// Trick: for mfma_16x16x32, A-frag (row=l15, k=8g+j) and B-frag (col=l15,
// k=8g+j) have identical per-lane addresses in a row-major source. One
// contiguous x load per lane serves as A (q,k: D=x*W row-major) or as B
// (v: D=(x*W)^T = vT layout directly).
// 512 blocks x 12 waves: wave = (y in q/k/v) x (n-tile 0..3), 16 t-rows.
// q scaled by (1/8)*log2(e) -- attention softmax runs in base-2.
// ---------------------------------------------------------------------------
__global__ __launch_bounds__(768) void proj_kernel(
    const float* __restrict__ x, const unsigned short* __restrict__ wt,
    unsigned short* __restrict__ qo, unsigned short* __restrict__ ko,
    unsigned short* __restrict__ vo)
{
    const int t0 = blockIdx.x << 4;
    const int tid = threadIdx.x;
    const int w = tid >> 6;          // 0..11
    const int y = w >> 2;            // 0=q, 1=k, 2=v
    const int nf = w & 3;            // n-tile within head
    const int lane = tid & 63;
    const int l15 = lane & 15;
    const int g = lane >> 4;

    const float* xp = x + (size_t)(t0 + l15) * CC + 8 * g;
    const unsigned short* wp = wt + ((size_t)y * HH + 16 * nf + l15) * CC + 8 * g;

    float4v acc = (float4v)0.0f;

    if (y < 2) {
#pragma unroll 4
        for (int k0 = 0; k0 < CC; k0 += 32) {
            ushort8 xb = cvt8(*(const float4v*)(xp + k0), *(const float4v*)(xp + k0 + 4));
            ushort8 wf = *(const ushort8*)(wp + k0);
            acc = mfma16(xb, wf, acc);            // D = x*W  [t][h]
        }
        const float sc = (y == 0) ? 0.125f * LOG2E : 1.0f;
        unsigned short* dst = (y == 0) ? qo : ko;
#pragma unroll
        for (int r = 0; r < 4; ++r)               // row = 4g+r (t), col = l15 (h)
            dst[(size_t)(t0 + 4 * g + r) * HH + 16 * nf + l15] = f2bf(acc[r] * sc);
    } else {
#pragma unroll 4
        for (int k0 = 0; k0 < CC; k0 += 32) {
            ushort8 xb = cvt8(*(const float4v*)(xp + k0), *(const float4v*)(xp + k0 + 4));
            ushort8 wf = *(const ushort8*)(wp + k0);
            acc = mfma16(wf, xb, acc);            // D = (x*W)^T  [h][t]
        }
        const int b = t0 >> 11;                   // t-tiles never straddle batches
        const int tl = (t0 & (TT - 1)) + l15;
#pragma unroll
        for (int r = 0; r < 4; ++r)               // row = 4g+r (h), col = l15 (t)
            vo[((size_t)b * HH + 16 * nf + 4 * g + r) * TT + tl] = f2bf(acc[r]);
    }
}

// ---------------------------------------------------------------------------
// Kernel 2: causal flash attention, base-2 softmax (log2e folded into q).
// 8 waves/block share 16 queries, strided KV chunks, LDS merge of partials.
// Register double-buffer of K fragments + early V loads hide L2 latency.
// ---------------------------------------------------------------------------
__global__ __launch_bounds__(512) void attn_kernel(
    const unsigned short* __restrict__ qw,
    const unsigned short* __restrict__ kw,
    const unsigned short* __restrict__ vw,
    float* __restrict__ out)
{
    __shared__ float om[8][16], ol[8][16];
    __shared__ __align__(16) float oo[8][16][64];

    const int idx = blockIdx.x;
    const int b = idx & (BB - 1);
    const int qt = (TT / 16 - 1) - (idx >> 2);    // heavy tiles first
    const int q0 = qt << 4;
    const int tid = threadIdx.x;
    const int w = tid >> 6;
    const int lane = tid & 63;
    const int l15 = lane & 15;
    const int g = lane >> 4;
    const int q = q0 + l15;

    const unsigned short* qrow = qw + (size_t)(b * TT + q) * HH + 8 * g;
    ushort8 qf0 = *(const ushort8*)qrow;
    ushort8 qf1 = *(const ushort8*)(qrow + 32);

    const unsigned short* kb = kw + (size_t)b * TT * HH;
    const unsigned short* vp_base = vw + (size_t)b * HH * TT;

    float m_run = -3.0e38f, l_run = 0.0f;
    float4v o[4];
#pragma unroll
    for (int i = 0; i < 4; ++i) o[i] = (float4v)0.0f;

    const int ks_end = q0 + 16;
    int kv0 = 32 * w;
    ushort8 k00, k01, k10, k11;
    if (kv0 < ks_end) {
        const unsigned short* kr = kb + (size_t)(kv0 + l15) * HH + 8 * g;
        k00 = *(const ushort8*)kr;
        k01 = *(const ushort8*)(kr + 32);
        k10 = *(const ushort8*)(kr + 16 * HH);
        k11 = *(const ushort8*)(kr + 16 * HH + 32);
    }

    for (; kv0 < ks_end; kv0 += 256) {
        // prefetch next chunk's K into the shadow regs
        ushort8 n00 = k00, n01 = k01, n10 = k10, n11 = k11;
        if (kv0 + 256 < ks_end) {
            const unsigned short* kr = kb + (size_t)(kv0 + 256 + l15) * HH + 8 * g;
            n00 = *(const ushort8*)kr;
            n01 = *(const ushort8*)(kr + 32);
            n10 = *(const ushort8*)(kr + 16 * HH);
            n11 = *(const ushort8*)(kr + 16 * HH + 32);
        }
        // V loads issued before the softmax chain
        ushort4v va[4], vb[4];
#pragma unroll
        for (int ht = 0; ht < 4; ++ht) {
            const unsigned short* vp = vp_base + (size_t)(16 * ht + l15) * TT + kv0 + 4 * g;
            va[ht] = *(const ushort4v*)vp;
            vb[ht] = *(const ushort4v*)(vp + 16);
        }

        float4v s0 = (float4v)0.0f, s1 = (float4v)0.0f;  // S^T: lane=q, reg=key
        s0 = mfma16(k00, qf0, s0);
        s0 = mfma16(k01, qf1, s0);
        s1 = mfma16(k10, qf0, s1);
        s1 = mfma16(k11, qf1, s1);

        if (kv0 + 31 > q0) {  // partial tile: causal mask
            const int kbase0 = kv0 + 4 * g;
#pragma unroll
            for (int r = 0; r < 4; ++r) {
                if (kbase0 + r > q) s0[r] = -1e30f;
                if (kbase0 + 16 + r > q) s1[r] = -1e30f;
            }
        }

        float mt = s0[0];
#pragma unroll
        for (int r = 1; r < 4; ++r) mt = fmaxf(mt, s0[r]);
#pragma unroll
        for (int r = 0; r < 4; ++r) mt = fmaxf(mt, s1[r]);
        mt = fmaxf(mt, __shfl_xor(mt, 16, 64));
        mt = fmaxf(mt, __shfl_xor(mt, 32, 64));

        const float m_new = fmaxf(m_run, mt);
        const float scale = exp2f(m_run - m_new);
        float p0[4], p1[4];
        float sum = 0.0f;
#pragma unroll
        for (int r = 0; r < 4; ++r) {
            p0[r] = exp2f(s0[r] - m_new);
            p1[r] = exp2f(s1[r] - m_new);
            sum += p0[r] + p1[r];
        }
        sum += __shfl_xor(sum, 16, 64);
        sum += __shfl_xor(sum, 32, 64);
        l_run = l_run * scale + sum;
        m_run = m_new;
#pragma unroll
        for (int i = 0; i < 4; ++i) o[i] *= scale;

        ushort8 bp;  // P^T fragment: kappa(g,j) = 16*(j>>2) + 4g + (j&3)
#pragma unroll
        for (int r = 0; r < 4; ++r) { bp[r] = f2bf(p0[r]); bp[4 + r] = f2bf(p1[r]); }

#pragma unroll
        for (int ht = 0; ht < 4; ++ht) {
            ushort8 av;
#pragma unroll
            for (int r = 0; r < 4; ++r) { av[r] = va[ht][r]; av[4 + r] = vb[ht][r]; }
            o[ht] = mfma16(av, bp, o[ht]);
        }

        k00 = n00; k01 = n01; k10 = n10; k11 = n11;
    }

    if (lane < 16) { om[w][lane] = m_run; ol[w][lane] = l_run; }
#pragma unroll
    for (int ht = 0; ht < 4; ++ht)
        *(float4v*)&oo[w][l15][16 * ht + 4 * g] = o[ht];
    __syncthreads();

    // merge 8 partials: 1024 (q,h) elems over 512 threads
#pragma unroll 2
    for (int e = tid; e < 16 * HH; e += 512) {
        const int qq = e >> 6, h = e & 63;
        float mstar = om[0][qq];
#pragma unroll
        for (int w2 = 1; w2 < 8; ++w2) mstar = fmaxf(mstar, om[w2][qq]);
        float lsum = 0.0f, osum = 0.0f;
#pragma unroll
        for (int w2 = 0; w2 < 8; ++w2) {
            const float al = exp2f(om[w2][qq] - mstar);
            lsum += al * ol[w2][qq];
            osum += al * oo[w2][qq][h];
        }
        out[((size_t)b * TT + q0 + qq) * HH + h] = osum / lsum;
    }
}

extern "C" void kernel_launch(void* const* d_in, const int* in_sizes, int n_in,
                              void* d_out, int out_size, void* d_ws, size_t ws_size,
                              hipStream_t stream) {
    // setup_inputs order: x, Wk, Wq, Wv
    const float* x  = (const float*)d_in[0];
    const float* Wk = (const float*)d_in[1];
    const float* Wq = (const float*)d_in[2];
    const float* Wv = (const float*)d_in[3];

    // ws: q bf16 [B*T][64] | k bf16 [B*T][64] | vT bf16 [B][64][T] | W^T bf16 [3][64][1024]
    unsigned short* q_ws  = (unsigned short*)d_ws;
    unsigned short* k_ws  = q_ws + (size_t)BB * TT * HH;
    unsigned short* vt_ws = k_ws + (size_t)BB * TT * HH;
    unsigned short* wt_ws = vt_ws + (size_t)BB * TT * HH;

    wconv_kernel<<<192, 256, 0, stream>>>(Wq, Wk, Wv, wt_ws);
    proj_kernel<<<BB * TT / 16, 768, 0, stream>>>(x, wt_ws, q_ws, k_ws, vt_ws);
    attn_kernel<<<BB * TT / 16, 512, 0, stream>>>(q_ws, k_ws, vt_ws, (float*)d_out);
}

// Round 4
// 59.661 us; speedup vs baseline: 1.8445x; 1.8445x over previous
//
#include <hip/hip_runtime.h>
#include <hip/hip_bf16.h>

#define BB 4
#define TT 2048
#define CC 1024
#define HH 64
#define LOG2E 1.4426950408889634f

typedef __attribute__((ext_vector_type(8))) unsigned short ushort8;
typedef __attribute__((ext_vector_type(4))) unsigned short ushort4v;
typedef __attribute__((ext_vector_type(8))) __bf16 bf16x8;
typedef __attribute__((ext_vector_type(4))) float float4v;

static __device__ __forceinline__ unsigned short f2bf(float f) {
    return __builtin_bit_cast(unsigned short, (__bf16)f);  // RNE, hw cvt
}

static __device__ __forceinline__ float4v mfma16(ushort8 a, ushort8 b, float4v c) {
    return __builtin_amdgcn_mfma_f32_16x16x32_bf16(
        __builtin_bit_cast(bf16x8, a), __builtin_bit_cast(bf16x8, b), c, 0, 0, 0);
}

#define GLDS16(gp, lp)                                                        \
    __builtin_amdgcn_global_load_lds(                                         \
        (const __attribute__((address_space(1))) unsigned int*)(gp),          \
        (__attribute__((address_space(3))) unsigned int*)(lp), 16, 0, 0)

// ---------------------------------------------------------------------------
// Kernel 0: pack W (f32 [C][64] x3) into MFMA-B-fragment-interleaved bf16:
// wf unit index U = ((kc*2 + ks)*12 + nt)*64 + lane, 8 bf16 per unit:
//   value[j] = W_y[kc*64 + ks*32 + 8*(lane>>4) + j][16*(nt&3) + (lane&15)]
// so proj's per-K-step W staging is a LINEAR 24KB copy (global_load_lds).
// 16 blocks (one per kc) x 256 thr; W staged coalesced into LDS first.
// ---------------------------------------------------------------------------
__global__ __launch_bounds__(256) void wconv_kernel(
    const float* __restrict__ Wq, const float* __restrict__ Wk,
    const float* __restrict__ Wv, unsigned short* __restrict__ wf)
{
    __shared__ __align__(16) float ws[3][64][64];  // 48KB
    const int kc = blockIdx.x;
    const int t = threadIdx.x;
    const int r = t >> 2, c4 = (t & 3) << 4;
    const float* Ws[3] = {Wq, Wk, Wv};
#pragma unroll
    for (int y = 0; y < 3; ++y) {
        const float* src = Ws[y] + (size_t)(kc * 64 + r) * HH + c4;
#pragma unroll
        for (int i = 0; i < 4; ++i)
            *(float4v*)&ws[y][r][c4 + 4 * i] = *(const float4v*)(src + 4 * i);
    }
    __syncthreads();
#pragma unroll
    for (int i = 0; i < 6; ++i) {
        const int U = t + 256 * i;            // 0..1535
        const int lane = U & 63, qq = U >> 6;
        const int nt = qq % 12, ks = qq / 12;
        const int y = nt >> 2;
        const int col = 16 * (nt & 3) + (lane & 15);
        const int kl = ks * 32 + 8 * (lane >> 4);
        ushort8 p;
#pragma unroll
        for (int j = 0; j < 8; ++j) p[j] = f2bf(ws[y][kl + j][col]);
        *(ushort8*)&wf[((size_t)kc * 1536 + U) * 8] = p;
    }
}

// ---------------------------------------------------------------------------
// Kernel 1: fused q/k/v projection, staged GEMM. 512 blocks x 4 waves.
// BM=16 rows, BK=64. W tiles: linear global_load_lds from wf (24KB/step).
// x tiles: coalesced f32 load -> cvt -> swizzled ds_write (2KB/step).
// Wave w owns n-tiles {3w..3w+2} of 12 (q0..3,k0..3,v0..3); v tiles use
// swapped mfma operands to produce vT[b][h][t] directly. 1 barrier/step.
// ---------------------------------------------------------------------------
__global__ __launch_bounds__(256) void proj_kernel(
    const float* __restrict__ x, const unsigned short* __restrict__ wf,
    unsigned short* __restrict__ qo, unsigned short* __restrict__ ko,
    unsigned short* __restrict__ vo)
{
    __shared__ __align__(16) unsigned short xa[2][1024];    // 2 x 2KB  (128 units)
    __shared__ __align__(16) unsigned short wb[2][12288];   // 2 x 24KB (1536 units)

    const int t0 = blockIdx.x << 4;
    const int tid = threadIdx.x;
    const int w = tid >> 6, lane = tid & 63;
    const int l15 = lane & 15, g = lane >> 4;

    // x staging decode: thread -> (row, 4 k-elems) -> swizzled 8B unit slot
    const int srow = tid >> 4;
    const int c0 = (tid & 15) << 2;                 // k-local 0..60
    const int su = ((c0 >> 5) << 6) + (((c0 >> 3) & 3) << 4) + srow;
    const int ssu = su ^ ((su >> 4) & 7);
    const int soff = ssu * 8 + (c0 & 4);            // ushort offset
    const float* xp = x + (size_t)(t0 + srow) * CC + c0;

    // A-frag read offsets (swizzled), per ks
    const int au0 = (lane ^ g) * 8;
    const int au1 = ((64 + lane) ^ (4 + g)) * 8;

    const int nt0 = 3 * w;
    float4v acc[3];
#pragma unroll
    for (int i = 0; i < 3; ++i) acc[i] = (float4v)0.0f;

    {   // prologue: stage kc=0
        float4v xv = *(const float4v*)xp;
        ushort4v xb;
#pragma unroll
        for (int i = 0; i < 4; ++i) xb[i] = f2bf(xv[i]);
        *(ushort4v*)&xa[0][soff] = xb;
#pragma unroll
        for (int i = 0; i < 6; ++i) {
            const int p = 6 * w + i;
            GLDS16(wf + (size_t)(p * 64 + lane) * 8, &wb[0][p * 512]);
        }
    }
    __syncthreads();

    for (int kc = 0; kc < 16; ++kc) {
        const int cur = kc & 1, nxt = cur ^ 1;
        float4v xv;
        if (kc < 15) {
            xv = *(const float4v*)(xp + (kc + 1) * 64);
#pragma unroll
            for (int i = 0; i < 6; ++i) {
                const int p = 6 * w + i;
                GLDS16(wf + (size_t)((kc + 1) * 1536 + p * 64 + lane) * 8,
                       &wb[nxt][p * 512]);
            }
        }
        ushort8 a0 = *(const ushort8*)&xa[cur][au0];
        ushort8 a1 = *(const ushort8*)&xa[cur][au1];
#pragma unroll
        for (int j = 0; j < 3; ++j) {
            const int nt = nt0 + j;
            ushort8 b0 = *(const ushort8*)&wb[cur][nt * 512 + lane * 8];
            ushort8 b1 = *(const ushort8*)&wb[cur][(12 + nt) * 512 + lane * 8];
            if (nt < 8) {       // q,k: D = x*W  (row=t, col=h)
                acc[j] = mfma16(a0, b0, acc[j]);
                acc[j] = mfma16(a1, b1, acc[j]);
            } else {            // v: D = (x*W)^T (row=h, col=t)
                acc[j] = mfma16(b0, a0, acc[j]);
                acc[j] = mfma16(b1, a1, acc[j]);
            }
        }
        if (kc < 15) {
            ushort4v xb;
#pragma unroll
            for (int i = 0; i < 4; ++i) xb[i] = f2bf(xv[i]);
            *(ushort4v*)&xa[nxt][soff] = xb;
        }
        __syncthreads();
    }

#pragma unroll
    for (int j = 0; j < 3; ++j) {
        const int nt = nt0 + j;
        if (nt < 4) {
#pragma unroll
            for (int r = 0; r < 4; ++r)
                qo[(size_t)(t0 + 4 * g + r) * HH + 16 * nt + l15] =
                    f2bf(acc[j][r] * (0.125f * LOG2E));
        } else if (nt < 8) {
#pragma unroll
            for (int r = 0; r < 4; ++r)
                ko[(size_t)(t0 + 4 * g + r) * HH + 16 * (nt - 4) + l15] =
                    f2bf(acc[j][r]);
        } else {
            const int b = t0 >> 11;
            const int tl = (t0 & (TT - 1)) + l15;
#pragma unroll
            for (int r = 0; r < 4; ++r)
                vo[((size_t)b * HH + 16 * (nt - 8) + 4 * g + r) * TT + tl] =
                    f2bf(acc[j][r]);
        }
    }
}

// ---------------------------------------------------------------------------
// Kernel 2: causal flash attention, KVBLK=64. 8 waves/block share 16 queries,
// strided 64-key chunks, LDS merge. Swapped QK^T keeps softmax in registers;
// PV reuses the S/P register layout as B-fragment (kappa trick per 32-key
// sub-chunk), V^T gathered to match. Base-2 softmax (log2e folded into q).
// ---------------------------------------------------------------------------
__global__ __launch_bounds__(512, 4) void attn_kernel(
    const unsigned short* __restrict__ qw,
    const unsigned short* __restrict__ kw,
    const unsigned short* __restrict__ vw,
    float* __restrict__ out)
{
    __shared__ float om[8][16], ol[8][16];
    __shared__ __align__(16) float oo[8][16][64];

    const int idx = blockIdx.x;
    const int b = idx & (BB - 1);
    const int qt = (TT / 16 - 1) - (idx >> 2);    // heavy tiles first
    const int q0 = qt << 4;
    const int tid = threadIdx.x;
    const int w = tid >> 6;
    const int lane = tid & 63;
    const int l15 = lane & 15;
    const int g = lane >> 4;
    const int q = q0 + l15;

    const unsigned short* qrow = qw + (size_t)(b * TT + q) * HH + 8 * g;
    ushort8 qf0 = *(const ushort8*)qrow;
    ushort8 qf1 = *(const ushort8*)(qrow + 32);

    const unsigned short* kb = kw + (size_t)b * TT * HH;
    const unsigned short* vb = vw + (size_t)b * HH * TT;

    float m_run = -3.0e38f, l_run = 0.0f;
    float4v o[4];
#pragma unroll
    for (int i = 0; i < 4; ++i) o[i] = (float4v)0.0f;

    for (int kv0 = 64 * w; kv0 < q0 + 16; kv0 += 512) {
        // K fragments: 4 key-subtiles x 2 h-halves
        const unsigned short* kr = kb + (size_t)(kv0 + l15) * HH + 8 * g;
        ushort8 akl[4], akh[4];
#pragma unroll
        for (int f = 0; f < 4; ++f) {
            akl[f] = *(const ushort8*)(kr + f * 16 * HH);
            akh[f] = *(const ushort8*)(kr + f * 16 * HH + 32);
        }
        // V fragments, issued before the softmax chain
        ushort8 av0[4], av1[4];
#pragma unroll
        for (int ht = 0; ht < 4; ++ht) {
            const unsigned short* vp = vb + (size_t)(16 * ht + l15) * TT + kv0 + 4 * g;
            ushort4v v0 = *(const ushort4v*)vp;
            ushort4v v1 = *(const ushort4v*)(vp + 16);
            ushort4v v2 = *(const ushort4v*)(vp + 32);
            ushort4v v3 = *(const ushort4v*)(vp + 48);
#pragma unroll
            for (int r = 0; r < 4; ++r) {
                av0[ht][r] = v0[r]; av0[ht][4 + r] = v1[r];
                av1[ht][r] = v2[r]; av1[ht][4 + r] = v3[r];
            }
        }

        float4v s[4];  // S^T: lane=q, key = kv0 + 16f + 4g + r
#pragma unroll
        for (int f = 0; f < 4; ++f) {
            s[f] = mfma16(akl[f], qf0, (float4v)0.0f);
            s[f] = mfma16(akh[f], qf1, s[f]);
        }

        if (kv0 + 63 > q0) {  // causal mask on partial tiles
#pragma unroll
            for (int f = 0; f < 4; ++f)
#pragma unroll
                for (int r = 0; r < 4; ++r)
                    if (kv0 + 16 * f + 4 * g + r > q) s[f][r] = -1e30f;
        }

        float mt = s[0][0];
#pragma unroll
        for (int f = 0; f < 4; ++f)
#pragma unroll
            for (int r = 0; r < 4; ++r) mt = fmaxf(mt, s[f][r]);
        mt = fmaxf(mt, __shfl_xor(mt, 16, 64));
        mt = fmaxf(mt, __shfl_xor(mt, 32, 64));

        const float m_new = fmaxf(m_run, mt);
        const float scale = exp2f(m_run - m_new);
        float p[4][4];
        float sum = 0.0f;
#pragma unroll
        for (int f = 0; f < 4; ++f)
#pragma unroll
            for (int r = 0; r < 4; ++r) {
                p[f][r] = exp2f(s[f][r] - m_new);
                sum += p[f][r];
            }
        sum += __shfl_xor(sum, 16, 64);
        sum += __shfl_xor(sum, 32, 64);
        l_run = l_run * scale + sum;
        m_run = m_new;
#pragma unroll
        for (int i = 0; i < 4; ++i) o[i] *= scale;

        ushort8 bp0, bp1;  // kappa(g,j) per 32-key sub-chunk
#pragma unroll
        for (int r = 0; r < 4; ++r) {
            bp0[r] = f2bf(p[0][r]); bp0[4 + r] = f2bf(p[1][r]);
            bp1[r] = f2bf(p[2][r]); bp1[4 + r] = f2bf(p[3][r]);
        }
#pragma unroll
        for (int ht = 0; ht < 4; ++ht) {
            o[ht] = mfma16(av0[ht], bp0, o[ht]);
            o[ht] = mfma16(av1[ht], bp1, o[ht]);
        }
    }

    if (lane < 16) { om[w][lane] = m_run; ol[w][lane] = l_run; }
#pragma unroll
    for (int ht = 0; ht < 4; ++ht)
        *(float4v*)&oo[w][l15][16 * ht + 4 * g] = o[ht];
    __syncthreads();

#pragma unroll 2
    for (int e = tid; e < 16 * HH; e += 512) {
        const int qq = e >> 6, h = e & 63;
        float mstar = om[0][qq];
#pragma unroll
        for (int w2 = 1; w2 < 8; ++w2) mstar = fmaxf(mstar, om[w2][qq]);
        float lsum = 0.0f, osum = 0.0f;
#pragma unroll
        for (int w2 = 0; w2 < 8; ++w2) {
            const float al = exp2f(om[w2][qq] - mstar);
            lsum += al * ol[w2][qq];
            osum += al * oo[w2][qq][h];
        }
        out[((size_t)b * TT + q0 + qq) * HH + h] = osum / lsum;
    }
}

extern "C" void kernel_launch(void* const* d_in, const int* in_sizes, int n_in,
                              void* d_out, int out_size, void* d_ws, size_t ws_size,
                              hipStream_t stream) {
    // setup_inputs order: x, Wk, Wq, Wv
    const float* x  = (const float*)d_in[0];
    const float* Wk = (const float*)d_in[1];
    const float* Wq = (const float*)d_in[2];
    const float* Wv = (const float*)d_in[3];

    // ws: q bf16 [B*T][64] | k bf16 [B*T][64] | vT bf16 [B][64][T] | wf bf16 frag-interleaved 384KB
    unsigned short* q_ws  = (unsigned short*)d_ws;
    unsigned short* k_ws  = q_ws + (size_t)BB * TT * HH;
    unsigned short* vt_ws = k_ws + (size_t)BB * TT * HH;
    unsigned short* wf_ws = vt_ws + (size_t)BB * TT * HH;

    wconv_kernel<<<16, 256, 0, stream>>>(Wq, Wk, Wv, wf_ws);
    proj_kernel<<<BB * TT / 16, 256, 0, stream>>>(x, wf_ws, q_ws, k_ws, vt_ws);
    attn_kernel<<<BB * TT / 16, 512, 0, stream>>>(q_ws, k_ws, vt_ws, (float*)d_out);
}

// Round 5
// 53.037 us; speedup vs baseline: 2.0748x; 1.1249x over previous
//
#include <hip/hip_runtime.h>
#include <hip/hip_bf16.h>

#define BB 4
#define TT 2048
#define CC 1024
#define HH 64
#define LOG2E 1.4426950408889634f

typedef __attribute__((ext_vector_type(8))) unsigned short ushort8;
typedef __attribute__((ext_vector_type(4))) unsigned short ushort4v;
typedef __attribute__((ext_vector_type(8))) __bf16 bf16x8;
typedef __attribute__((ext_vector_type(4))) float float4v;

static __device__ __forceinline__ unsigned short f2bf(float f) {
    return __builtin_bit_cast(unsigned short, (__bf16)f);  // RNE, hw cvt
}

static __device__ __forceinline__ float4v mfma16(ushort8 a, ushort8 b, float4v c) {
    return __builtin_amdgcn_mfma_f32_16x16x32_bf16(
        __builtin_bit_cast(bf16x8, a), __builtin_bit_cast(bf16x8, b), c, 0, 0, 0);
}

static __device__ __forceinline__ ushort8 cvt8(float4v a, float4v b) {
    ushort8 r;
#pragma unroll
    for (int i = 0; i < 4; ++i) { r[i] = f2bf(a[i]); r[4 + i] = f2bf(b[i]); }
    return r;
}

// ---------------------------------------------------------------------------
// Kernel 0: pack W (f32 [C][64] x3) into MFMA-B-fragment-interleaved bf16:
// unit U = ((kc*2 + ks)*12 + nt)*64 + lane, 8 bf16/unit:
//   value[j] = W_y[kc*64 + ks*32 + 8*(lane>>4) + j][16*(nt&3) + (lane&15)]
// so proj's W-fragment register fill is a linear coalesced 16B/lane stream.
// ---------------------------------------------------------------------------
__global__ __launch_bounds__(256) void wconv_kernel(
    const float* __restrict__ Wq, const float* __restrict__ Wk,
    const float* __restrict__ Wv, unsigned short* __restrict__ wf)
{
    __shared__ __align__(16) float ws[3][64][64];  // 48KB
    const int kc = blockIdx.x;
    const int t = threadIdx.x;
    const int r = t >> 2, c4 = (t & 3) << 4;
    const float* Ws[3] = {Wq, Wk, Wv};
#pragma unroll
    for (int y = 0; y < 3; ++y) {
        const float* src = Ws[y] + (size_t)(kc * 64 + r) * HH + c4;
#pragma unroll
        for (int i = 0; i < 4; ++i)
            *(float4v*)&ws[y][r][c4 + 4 * i] = *(const float4v*)(src + 4 * i);
    }
    __syncthreads();
#pragma unroll
    for (int i = 0; i < 6; ++i) {
        const int U = t + 256 * i;            // 0..1535
        const int lane = U & 63, qq = U >> 6;
        const int nt = qq % 12, ks = qq / 12;
        const int y = nt >> 2;
        const int col = 16 * (nt & 3) + (lane & 15);
        const int kl = ks * 32 + 8 * (lane >> 4);
        ushort8 p;
#pragma unroll
        for (int j = 0; j < 8; ++j) p[j] = f2bf(ws[y][kl + j][col]);
        *(ushort8*)&wf[((size_t)kc * 1536 + U) * 8] = p;
    }
}

// ---------------------------------------------------------------------------
// Kernel 1: fused q/k/v projection, W-STATIONARY. 256 blocks x 12 waves.
// Wave w = (y,nf) holds its full K=1024 W-fragment set in 64 VGPRs (32
// linear 16B loads). K-loop stages only the 4KB x-tile (32 rows x 64 k),
// double-buffered + XOR-swizzled, 1 barrier/step, 4 MFMAs/wave/step.
// v waves (w>=8) swap MFMA operands to emit vT[b][h][t] directly.
// ---------------------------------------------------------------------------
__global__ __launch_bounds__(768) void proj_kernel(
    const float* __restrict__ x, const unsigned short* __restrict__ wf,
    unsigned short* __restrict__ qo, unsigned short* __restrict__ ko,
    unsigned short* __restrict__ vo)
{
    __shared__ __align__(16) unsigned short xa[2][2048];   // 2 x 4KB, 16B units

    const int t0 = blockIdx.x << 5;                        // 32 rows
    const int tid = threadIdx.x;
    const int w = tid >> 6;                                // 0..11 = (y,nf)
    const int lane = tid & 63;
    const int l15 = lane & 15, g = lane >> 4;

    // resident W fragments (linear coalesced fill from wf)
    ushort8 bw[16][2];
#pragma unroll
    for (int kc = 0; kc < 16; ++kc)
#pragma unroll
        for (int ks = 0; ks < 2; ++ks)
            bw[kc][ks] = *(const ushort8*)
                &wf[(size_t)(((kc * 2 + ks) * 12 + w) * 64 + lane) * 8];

    // x staging: threads 0..255, 8 f32 -> 8 bf16 (one swizzled 16B unit)
    const int sr = tid >> 3, su = tid & 7;
    const int soff = (sr * 8 + (su ^ (sr & 7))) * 8;
    const float* xp = x + (size_t)(t0 + sr) * CC + su * 8;

    // swizzled A-frag read offsets (2-way max on b128 = free)
    const int sw = l15 & 7;
    const int r00 = (l15 * 8 + (g ^ sw)) * 8;
    const int r01 = (l15 * 8 + ((4 + g) ^ sw)) * 8;
    const int r10 = ((16 + l15) * 8 + (g ^ sw)) * 8;
    const int r11 = ((16 + l15) * 8 + ((4 + g) ^ sw)) * 8;

    float4v ac0 = (float4v)0.0f, ac1 = (float4v)0.0f;

    if (tid < 256)
        *(ushort8*)&xa[0][soff] =
            cvt8(*(const float4v*)xp, *(const float4v*)(xp + 4));
    __syncthreads();

#pragma unroll
    for (int kc = 0; kc < 16; ++kc) {
        const int cur = kc & 1, nxt = cur ^ 1;
        float4v u0, u1;
        if (kc < 15 && tid < 256) {
            u0 = *(const float4v*)(xp + (kc + 1) * 64);
            u1 = *(const float4v*)(xp + (kc + 1) * 64 + 4);
        }
        const unsigned short* xb = xa[cur];
        ushort8 a00 = *(const ushort8*)&xb[r00];
        ushort8 a01 = *(const ushort8*)&xb[r01];
        ushort8 a10 = *(const ushort8*)&xb[r10];
        ushort8 a11 = *(const ushort8*)&xb[r11];
        if (w < 8) {                      // q,k: D = x*W   (row=t, col=h)
            ac0 = mfma16(a00, bw[kc][0], ac0);
            ac0 = mfma16(a01, bw[kc][1], ac0);
            ac1 = mfma16(a10, bw[kc][0], ac1);
            ac1 = mfma16(a11, bw[kc][1], ac1);
        } else {                          // v: D = (x*W)^T (row=h, col=t)
            ac0 = mfma16(bw[kc][0], a00, ac0);
            ac0 = mfma16(bw[kc][1], a01, ac0);
            ac1 = mfma16(bw[kc][0], a10, ac1);
            ac1 = mfma16(bw[kc][1], a11, ac1);
        }
        if (kc < 15 && tid < 256)
            *(ushort8*)&xa[nxt][soff] = cvt8(u0, u1);
        __syncthreads();
    }

    if (w < 8) {
        const float sc = (w < 4) ? 0.125f * LOG2E : 1.0f;
        unsigned short* dst = (w < 4) ? qo : ko;
        const int nf = w & 3;
#pragma unroll
        for (int mt = 0; mt < 2; ++mt) {
            float4v a = mt ? ac1 : ac0;
#pragma unroll
            for (int r = 0; r < 4; ++r)
                dst[(size_t)(t0 + 16 * mt + 4 * g + r) * HH + 16 * nf + l15] =
                    f2bf(a[r] * sc);
        }
    } else {
        const int nf = w - 8;
        const int b = t0 >> 11, tl = t0 & (TT - 1);
#pragma unroll
        for (int mt = 0; mt < 2; ++mt) {
            float4v a = mt ? ac1 : ac0;
#pragma unroll
            for (int r = 0; r < 4; ++r)
                vo[((size_t)b * HH + 16 * nf + 4 * g + r) * TT + tl + 16 * mt + l15] =
                    f2bf(a[r]);
        }
    }
}

// ---------------------------------------------------------------------------
// Kernel 2: causal flash attention, KVBLK=128/wave-iter. 8 waves/block share
// 16 queries, strided 128-key chunks (stride 1024), LDS merge. Swapped QK^T
// keeps softmax in registers (2 shfl_xor); PV reuses the S/P register layout
// as B-fragment (kappa trick per 32-key group), V^T gathered to match.
// Base-2 softmax (log2e folded into q by proj).
// ---------------------------------------------------------------------------
__global__ __launch_bounds__(512) void attn_kernel(
    const unsigned short* __restrict__ qw,
    const unsigned short* __restrict__ kw,
    const unsigned short* __restrict__ vw,
    float* __restrict__ out)
{
    __shared__ float om[8][16], ol[8][16];
    __shared__ __align__(16) float oo[8][16][64];

    const int idx = blockIdx.x;
    const int b = idx & (BB - 1);
    const int qt = (TT / 16 - 1) - (idx >> 2);    // heavy tiles first
    const int q0 = qt << 4;
    const int tid = threadIdx.x;
    const int w = tid >> 6;
    const int lane = tid & 63;
    const int l15 = lane & 15;
    const int g = lane >> 4;
    const int q = q0 + l15;

    const unsigned short* qrow = qw + (size_t)(b * TT + q) * HH + 8 * g;
    ushort8 qf0 = *(const ushort8*)qrow;
    ushort8 qf1 = *(const ushort8*)(qrow + 32);

    const unsigned short* kb = kw + (size_t)b * TT * HH;
    const unsigned short* vb = vw + (size_t)b * HH * TT;

    float m_run = -3.0e38f, l_run = 0.0f;
    float4v o[4];
#pragma unroll
    for (int i = 0; i < 4; ++i) o[i] = (float4v)0.0f;

    for (int kv0 = 128 * w; kv0 < q0 + 16; kv0 += 1024) {
        // K fragments: 8 key-subtiles x 2 h-halves (issued as one batch)
        const unsigned short* kr = kb + (size_t)(kv0 + l15) * HH + 8 * g;
        ushort8 akl[8], akh[8];
#pragma unroll
        for (int f = 0; f < 8; ++f) {
            akl[f] = *(const ushort8*)(kr + f * 16 * HH);
            akh[f] = *(const ushort8*)(kr + f * 16 * HH + 32);
        }
        // V fragments (kappa-packed per 32-key group), issued before softmax
        ushort8 av[4][4];
#pragma unroll
        for (int ht = 0; ht < 4; ++ht) {
            const unsigned short* vp = vb + (size_t)(16 * ht + l15) * TT + kv0 + 4 * g;
#pragma unroll
            for (int g2 = 0; g2 < 4; ++g2) {
                ushort4v v0 = *(const ushort4v*)(vp + 32 * g2);
                ushort4v v1 = *(const ushort4v*)(vp + 32 * g2 + 16);
#pragma unroll
                for (int r = 0; r < 4; ++r) {
                    av[ht][g2][r] = v0[r]; av[ht][g2][4 + r] = v1[r];
                }
            }
        }

        float4v s[8];  // S^T: lane=q, key = kv0 + 16f + 4g + r
#pragma unroll
        for (int f = 0; f < 8; ++f) {
            s[f] = mfma16(akl[f], qf0, (float4v)0.0f);
            s[f] = mfma16(akh[f], qf1, s[f]);
        }

        if (kv0 + 127 > q0) {  // causal mask on boundary chunks
#pragma unroll
            for (int f = 0; f < 8; ++f)
#pragma unroll
                for (int r = 0; r < 4; ++r)
                    if (kv0 + 16 * f + 4 * g + r > q) s[f][r] = -1e30f;
        }

        float mt = s[0][0];
#pragma unroll
        for (int f = 0; f < 8; ++f)
#pragma unroll
            for (int r = 0; r < 4; ++r) mt = fmaxf(mt, s[f][r]);
        mt = fmaxf(mt, __shfl_xor(mt, 16, 64));
        mt = fmaxf(mt, __shfl_xor(mt, 32, 64));

        const float m_new = fmaxf(m_run, mt);
        const float scale = exp2f(m_run - m_new);
        float sum = 0.0f;
#pragma unroll
        for (int f = 0; f < 8; ++f)
#pragma unroll
            for (int r = 0; r < 4; ++r) {
                s[f][r] = exp2f(s[f][r] - m_new);   // P in place of S
                sum += s[f][r];
            }
        sum += __shfl_xor(sum, 16, 64);
        sum += __shfl_xor(sum, 32, 64);
        l_run = l_run * scale + sum;
        m_run = m_new;
#pragma unroll
        for (int i = 0; i < 4; ++i) o[i] *= scale;

        ushort8 bp[4];  // kappa(g,j) per 32-key group
#pragma unroll
        for (int g2 = 0; g2 < 4; ++g2)
#pragma unroll
            for (int r = 0; r < 4; ++r) {
                bp[g2][r] = f2bf(s[2 * g2][r]);
                bp[g2][4 + r] = f2bf(s[2 * g2 + 1][r]);
            }
#pragma unroll
        for (int ht = 0; ht < 4; ++ht)
#pragma unroll
            for (int g2 = 0; g2 < 4; ++g2)
                o[ht] = mfma16(av[ht][g2], bp[g2], o[ht]);
    }

    if (lane < 16) { om[w][lane] = m_run; ol[w][lane] = l_run; }
#pragma unroll
    for (int ht = 0; ht < 4; ++ht)
        *(float4v*)&oo[w][l15][16 * ht + 4 * g] = o[ht];
    __syncthreads();

#pragma unroll 2
    for (int e = tid; e < 16 * HH; e += 512) {
        const int qq = e >> 6, h = e & 63;
        float mstar = om[0][qq];
#pragma unroll
        for (int w2 = 1; w2 < 8; ++w2) mstar = fmaxf(mstar, om[w2][qq]);
        float lsum = 0.0f, osum = 0.0f;
#pragma unroll
        for (int w2 = 0; w2 < 8; ++w2) {
            const float al = exp2f(om[w2][qq] - mstar);
            lsum += al * ol[w2][qq];
            osum += al * oo[w2][qq][h];
        }
        out[((size_t)b * TT + q0 + qq) * HH + h] = osum / lsum;
    }
}

extern "C" void kernel_launch(void* const* d_in, const int* in_sizes, int n_in,
                              void* d_out, int out_size, void* d_ws, size_t ws_size,
                              hipStream_t stream) {
    // setup_inputs order: x, Wk, Wq, Wv
    const float* x  = (const float*)d_in[0];
    const float* Wk = (const float*)d_in[1];
    const float* Wq = (const float*)d_in[2];
    const float* Wv = (const float*)d_in[3];

    // ws: q bf16 [B*T][64] | k bf16 [B*T][64] | vT bf16 [B][64][T] | wf 384KB
    unsigned short* q_ws  = (unsigned short*)d_ws;
    unsigned short* k_ws  = q_ws + (size_t)BB * TT * HH;
    unsigned short* vt_ws = k_ws + (size_t)BB * TT * HH;
    unsigned short* wf_ws = vt_ws + (size_t)BB * TT * HH;

    wconv_kernel<<<16, 256, 0, stream>>>(Wq, Wk, Wv, wf_ws);
    proj_kernel<<<BB * TT / 32, 768, 0, stream>>>(x, wf_ws, q_ws, k_ws, vt_ws);
    attn_kernel<<<BB * TT / 16, 512, 0, stream>>>(q_ws, k_ws, vt_ws, (float*)d_out);
}